// Round 14
// baseline (82.973 us; speedup 1.0000x reference)
//
#include <hip/hip_runtime.h>
#include <hip/hip_bf16.h>

namespace {

constexpr int Bc = 4, Hc = 16, Sc = 2048, Dc = 64;

using bf16x2 = __attribute__((ext_vector_type(2))) __bf16;
using bf16x8 = __attribute__((ext_vector_type(8))) __bf16;
using f32x4  = __attribute__((ext_vector_type(4))) float;
using f32x16 = __attribute__((ext_vector_type(16))) float;
using uint4v = __attribute__((ext_vector_type(4))) unsigned int;

__device__ __forceinline__ float exp2_hw(float x) {
#if __has_builtin(__builtin_amdgcn_exp2f)
  return __builtin_amdgcn_exp2f(x);
#else
  return exp2f(x);
#endif
}

__device__ __forceinline__ unsigned pk_bf16(float a, float b) {
  bf16x2 t = { (__bf16)a, (__bf16)b };
  return __builtin_bit_cast(unsigned, t);
}

// v_permlane32_swap_b32 a,b with s_nop hazard padding (raw asm bypasses the
// post-RA hazard recognizer). Operands must be DISTINCT live values.
__device__ __forceinline__ void pl32swap(unsigned& a, unsigned& b) {
  asm volatile("s_nop 1\n\tv_permlane32_swap_b32 %0, %1\n\ts_nop 1"
               : "+v"(a), "+v"(b));
}
// Early-clobber dual-mov guarantees the two swap operands sit in distinct regs
// (round-3 lesson: copies of one SSA value may share a VGPR).
__device__ __forceinline__ void xhalf_pair(float x, float& lo, float& hi) {
  unsigned a, b;
  asm volatile("v_mov_b32 %0, %2\n\t"
               "v_mov_b32 %1, %2\n\t"
               "s_nop 1\n\t"
               "v_permlane32_swap_b32 %0, %1\n\t"
               "s_nop 1"
               : "=&v"(a), "=&v"(b)
               : "v"(x));
  lo = __builtin_bit_cast(float, a);
  hi = __builtin_bit_cast(float, b);
}
__device__ __forceinline__ float xhalf_sum(float x) {
  float lo, hi; xhalf_pair(x, lo, hi); return lo + hi;
}

__device__ __forceinline__ int vswz(int d) { return ((d >> 4) ^ d) & 7; }

// ROUND-14 = round-13 (T15 pipeline, 64 us best) + 2-DEEP LOAD PIPELINE.
// Diagnosis: per-XCD K/V working set (8 bh x 1MB) > 4MB L2, so staging loads
// return from L3/HBM (~600-900cy) > the ~500cy compute span -> every tile all
// waves stall at the STAGE_WRITE's vmcnt, then the barrier. Fix (T3/T4
// counted-vmcnt): issue tile t+2 loads at iter t; stage-write tile t+1 from
// regs loaded at iter t-1 -> compiler emits vmcnt(8) (8 newer outstanding),
// each load gets a full tile period + compute to return. Register ping-pong
// (sets A/B) is static via an even/odd double-stepped loop (rule #20).
__global__ __launch_bounds__(256, 2)
void fattn_kernel(const float* __restrict__ Q, const float* __restrict__ K,
                  const float* __restrict__ V, float* __restrict__ O) {
  const int tid  = threadIdx.x;
  const int wid  = tid >> 6;
  const int lane = tid & 63;
  const int l31  = lane & 31;
  const int hi   = lane >> 5;

  // XCD-bijective swizzle; pair-panels {p, 15-p} -> every block = 34 tiles.
  const int flat = blockIdx.x + 8 * blockIdx.y;
  const int w    = (flat & 7) * 64 + (flat >> 3);
  const int p    = w & 7;
  const int bh   = w >> 3;

  const size_t base = (size_t)bh * (Sc * Dc);
  const float* Qb = Q + base;
  const float* Kb = K + base;
  const float* Vb = V + base;
  float*       Ob = O + base;

  __shared__ __align__(16) __bf16 k_lds[3][64][64];   // K[k][d],  col ^= (k&7)<<3
  __shared__ __align__(16) __bf16 vt_lds[3][64][64];  // V^T[d][k], k ^= vswz(d)<<3

  const int srow = tid >> 2;         // staging row 0..63
  const int scol = (tid & 3) * 16;   // staging col chunk
  const int ssw  = (srow & 7) << 3;

  constexpr float QSC = 0.125f * 1.44269504088896f;  // 1/sqrt(D) * log2(e)

#define BODY(T, SI, SW)                                                         \
  {                                                                             \
    const int kbase_ = (T) * 64;                                                \
    const bool doQK_ = ((T) < nkb) && ((T) <= tl);                              \
    const bool doPV_ = ((T) >= 1) && ((T) - 1 <= tl);                           \
    const bool preL_ = ((T) + 2 < nkb);                                         \
    const bool preW_ = ((T) + 1 < nkb);                                         \
    const int bp_ = (bq + 2 >= 3) ? bq - 1 : bq + 2;                            \
    const int bw_ = (bq + 1 >= 3) ? bq - 2 : bq + 1;                            \
    if (preL_) {                                                                \
      const float* ksrc_ = Kb + (size_t)(kbase_ + 128 + srow) * Dc + scol;      \
      SI##k0 = *(const f32x4*)ksrc_;                                            \
      SI##k1 = *(const f32x4*)(ksrc_ + 4);                                      \
      SI##k2 = *(const f32x4*)(ksrc_ + 8);                                      \
      SI##k3 = *(const f32x4*)(ksrc_ + 12);                                     \
      const float* vsrc_ = Vb + (size_t)(kbase_ + 128 + srow) * Dc + scol;      \
      SI##v0 = *(const f32x4*)vsrc_;                                            \
      SI##v1 = *(const f32x4*)(vsrc_ + 4);                                      \
      SI##v2 = *(const f32x4*)(vsrc_ + 8);                                      \
      SI##v3 = *(const f32x4*)(vsrc_ + 12);                                     \
    }                                                                           \
    f32x16 s0_, s1_;                                                            \
    if (doQK_) {                                                                \
      _Pragma("unroll")                                                         \
      for (int i = 0; i < 16; ++i) { s0_[i] = 0.f; s1_[i] = 0.f; }              \
      const int ksw_ = (l31 & 7) << 3;                                          \
      __builtin_amdgcn_s_setprio(1);                                            \
      _Pragma("unroll")                                                         \
      for (int s = 0; s < 4; ++s) {                                             \
        bf16x8 kf_ = *(const bf16x8*)&k_lds[bq][l31][(s * 16 + hi * 8) ^ ksw_]; \
        s0_ = __builtin_amdgcn_mfma_f32_32x32x16_bf16(kf_, qf[s], s0_, 0, 0, 0);\
      }                                                                         \
      _Pragma("unroll")                                                         \
      for (int s = 0; s < 4; ++s) {                                             \
        bf16x8 kf_ = *(const bf16x8*)&k_lds[bq][32 + l31][(s * 16 + hi * 8) ^ ksw_]; \
        s1_ = __builtin_amdgcn_mfma_f32_32x32x16_bf16(kf_, qf[s], s1_, 0, 0, 0);\
      }                                                                         \
      __builtin_amdgcn_s_setprio(0);                                            \
    }                                                                           \
    if (doPV_) {                                                                \
      const int vd0_ = l31, vd1_ = 32 + l31;                                    \
      const int vs0_ = vswz(vd0_) << 3, vs1_ = vswz(vd1_) << 3;                 \
      const __bf16 (*vc_)[64] = vt_lds[bp_];                                    \
      bf16x8 vf_;                                                               \
      __builtin_amdgcn_s_setprio(1);                                            \
      vf_ = *(const bf16x8*)&vc_[vd0_][(hi * 8) ^ vs0_];                        \
      o0 = __builtin_amdgcn_mfma_f32_32x32x16_bf16(vf_, pfp0, o0, 0, 0, 0);     \
      vf_ = *(const bf16x8*)&vc_[vd0_][(16 + hi * 8) ^ vs0_];                   \
      o0 = __builtin_amdgcn_mfma_f32_32x32x16_bf16(vf_, pfp1, o0, 0, 0, 0);     \
      vf_ = *(const bf16x8*)&vc_[vd0_][(32 + hi * 8) ^ vs0_];                   \
      o0 = __builtin_amdgcn_mfma_f32_32x32x16_bf16(vf_, pfp2, o0, 0, 0, 0);     \
      vf_ = *(const bf16x8*)&vc_[vd0_][(48 + hi * 8) ^ vs0_];                   \
      o0 = __builtin_amdgcn_mfma_f32_32x32x16_bf16(vf_, pfp3, o0, 0, 0, 0);     \
      vf_ = *(const bf16x8*)&vc_[vd1_][(hi * 8) ^ vs1_];                        \
      o1 = __builtin_amdgcn_mfma_f32_32x32x16_bf16(vf_, pfp0, o1, 0, 0, 0);     \
      vf_ = *(const bf16x8*)&vc_[vd1_][(16 + hi * 8) ^ vs1_];                   \
      o1 = __builtin_amdgcn_mfma_f32_32x32x16_bf16(vf_, pfp1, o1, 0, 0, 0);     \
      vf_ = *(const bf16x8*)&vc_[vd1_][(32 + hi * 8) ^ vs1_];                   \
      o1 = __builtin_amdgcn_mfma_f32_32x32x16_bf16(vf_, pfp2, o1, 0, 0, 0);     \
      vf_ = *(const bf16x8*)&vc_[vd1_][(48 + hi * 8) ^ vs1_];                   \
      o1 = __builtin_amdgcn_mfma_f32_32x32x16_bf16(vf_, pfp3, o1, 0, 0, 0);     \
      __builtin_amdgcn_s_setprio(0);                                            \
    }                                                                           \
    if (doQK_) {                                                                \
      if (kbase_ + 63 > wq) {                                                   \
        const int q_   = wq + l31;                                              \
        const int dq0_ = q_ - (kbase_ + 4 * hi);                                \
        const int dq1_ = q_ - (kbase_ + 32 + 4 * hi);                           \
        _Pragma("unroll")                                                       \
        for (int i = 0; i < 16; ++i) {                                          \
          const int off_ = (i & 3) + 8 * (i >> 2);                              \
          if (off_ > dq0_) s0_[i] = -1e30f;                                     \
          if (off_ > dq1_) s1_[i] = -1e30f;                                     \
        }                                                                       \
      }                                                                         \
      _Pragma("unroll")                                                         \
      for (int i = 0; i < 16; ++i) {                                            \
        s0_[i] = exp2_hw(s0_[i]);                                               \
        s1_[i] = exp2_hw(s1_[i]);                                               \
      }                                                                         \
      float sm_[16];                                                            \
      _Pragma("unroll")                                                         \
      for (int i = 0; i < 16; ++i) sm_[i] = s0_[i] + s1_[i];                    \
      _Pragma("unroll")                                                         \
      for (int st = 8; st > 0; st >>= 1)                                        \
        _Pragma("unroll")                                                       \
        for (int i = 0; i < st; ++i) sm_[i] += sm_[i + st];                     \
      l += xhalf_sum(sm_[0]);                                                   \
      uint4v wv_;                                                               \
      unsigned t0_, t1_, t2_, t3_;                                              \
      t0_ = pk_bf16(s0_[0], s0_[1]);  t1_ = pk_bf16(s0_[2], s0_[3]);            \
      t2_ = pk_bf16(s0_[4], s0_[5]);  t3_ = pk_bf16(s0_[6], s0_[7]);            \
      pl32swap(t0_, t2_); pl32swap(t1_, t3_);                                   \
      wv_[0] = t0_; wv_[1] = t1_; wv_[2] = t2_; wv_[3] = t3_;                   \
      pfp0 = __builtin_bit_cast(bf16x8, wv_);                                   \
      t0_ = pk_bf16(s0_[8], s0_[9]);   t1_ = pk_bf16(s0_[10], s0_[11]);         \
      t2_ = pk_bf16(s0_[12], s0_[13]); t3_ = pk_bf16(s0_[14], s0_[15]);         \
      pl32swap(t0_, t2_); pl32swap(t1_, t3_);                                   \
      wv_[0] = t0_; wv_[1] = t1_; wv_[2] = t2_; wv_[3] = t3_;                   \
      pfp1 = __builtin_bit_cast(bf16x8, wv_);                                   \
      t0_ = pk_bf16(s1_[0], s1_[1]);  t1_ = pk_bf16(s1_[2], s1_[3]);            \
      t2_ = pk_bf16(s1_[4], s1_[5]);  t3_ = pk_bf16(s1_[6], s1_[7]);            \
      pl32swap(t0_, t2_); pl32swap(t1_, t3_);                                   \
      wv_[0] = t0_; wv_[1] = t1_; wv_[2] = t2_; wv_[3] = t3_;                   \
      pfp2 = __builtin_bit_cast(bf16x8, wv_);                                   \
      t0_ = pk_bf16(s1_[8], s1_[9]);   t1_ = pk_bf16(s1_[10], s1_[11]);         \
      t2_ = pk_bf16(s1_[12], s1_[13]); t3_ = pk_bf16(s1_[14], s1_[15]);         \
      pl32swap(t0_, t2_); pl32swap(t1_, t3_);                                   \
      wv_[0] = t0_; wv_[1] = t1_; wv_[2] = t2_; wv_[3] = t3_;                   \
      pfp3 = __builtin_bit_cast(bf16x8, wv_);                                   \
    }                                                                           \
    if (preW_) {                                                                \
      uint4v w0_, w1_;                                                          \
      w0_[0] = pk_bf16(SW##k0[0], SW##k0[1]); w0_[1] = pk_bf16(SW##k0[2], SW##k0[3]); \
      w0_[2] = pk_bf16(SW##k1[0], SW##k1[1]); w0_[3] = pk_bf16(SW##k1[2], SW##k1[3]); \
      w1_[0] = pk_bf16(SW##k2[0], SW##k2[1]); w1_[1] = pk_bf16(SW##k2[2], SW##k2[3]); \
      w1_[2] = pk_bf16(SW##k3[0], SW##k3[1]); w1_[3] = pk_bf16(SW##k3[2], SW##k3[3]); \
      *(uint4v*)&k_lds[bw_][srow][scol ^ ssw]       = w0_;                      \
      *(uint4v*)&k_lds[bw_][srow][(scol + 8) ^ ssw] = w1_;                      \
      _Pragma("unroll")                                                         \
      for (int e = 0; e < 4; ++e) {                                             \
        vt_lds[bw_][scol + e     ][srow ^ (vswz(scol + e     ) << 3)] = (__bf16)SW##v0[e]; \
        vt_lds[bw_][scol + 4 + e ][srow ^ (vswz(scol + 4 + e ) << 3)] = (__bf16)SW##v1[e]; \
        vt_lds[bw_][scol + 8 + e ][srow ^ (vswz(scol + 8 + e ) << 3)] = (__bf16)SW##v2[e]; \
        vt_lds[bw_][scol + 12 + e][srow ^ (vswz(scol + 12 + e) << 3)] = (__bf16)SW##v3[e]; \
      }                                                                         \
    }                                                                           \
    if ((T) < nkb) __syncthreads();                                             \
    bq = bw_;                                                                   \
  }

  for (int half = 0; half < 2; ++half) {
    const int qp = half ? (15 - p) : p;
    const int qb = qp * 128;
    const int wq = qb + wid * 32;
    const int nkb = 2 * qp + 2;
    const int tl  = 2 * qp + (wid >> 1);   // last causally-active tile for wave

    // ---- Q fragment: lane holds Q[wq + l31][d = s*16 + hi*8 + j] ----
    bf16x8 qf[4];
    {
      const float* qrow = Qb + (size_t)(wq + l31) * Dc;
      #pragma unroll
      for (int s = 0; s < 4; ++s) {
        const float* src = qrow + s * 16 + hi * 8;
        f32x4 a0 = *(const f32x4*)src;
        f32x4 a1 = *(const f32x4*)(src + 4);
        uint4v wv;
        wv[0] = pk_bf16(a0[0] * QSC, a0[1] * QSC);
        wv[1] = pk_bf16(a0[2] * QSC, a0[3] * QSC);
        wv[2] = pk_bf16(a1[0] * QSC, a1[1] * QSC);
        wv[3] = pk_bf16(a1[2] * QSC, a1[3] * QSC);
        qf[s] = __builtin_bit_cast(bf16x8, wv);
      }
    }

    f32x16 o0, o1;
    #pragma unroll
    for (int i = 0; i < 16; ++i) { o0[i] = 0.f; o1[i] = 0.f; }
    float l = 0.f;
    bf16x8 pfp0, pfp1, pfp2, pfp3;   // P fragments of tile t-1 (cross-iter)

    // in-flight staging register sets: even tiles (>=2) in A, odd tiles in B
    f32x4 Ak0, Ak1, Ak2, Ak3, Av0, Av1, Av2, Av3;
    f32x4 Bk0, Bk1, Bk2, Bk3, Bv0, Bv1, Bv2, Bv3;

    // ---- prologue: tile 0 -> LDS buffer 0 directly; tile 1 loads -> set B ----
    {
      const float* ksrc = Kb + (size_t)srow * Dc + scol;
      f32x4 a0 = *(const f32x4*)ksrc;
      f32x4 a1 = *(const f32x4*)(ksrc + 4);
      f32x4 a2 = *(const f32x4*)(ksrc + 8);
      f32x4 a3 = *(const f32x4*)(ksrc + 12);
      const float* vsrc = Vb + (size_t)srow * Dc + scol;
      f32x4 b0 = *(const f32x4*)vsrc;
      f32x4 b1 = *(const f32x4*)(vsrc + 4);
      f32x4 b2 = *(const f32x4*)(vsrc + 8);
      f32x4 b3 = *(const f32x4*)(vsrc + 12);
      // tile 1 loads issued here (nkb >= 2 always)
      const float* ksrc1 = Kb + (size_t)(64 + srow) * Dc + scol;
      Bk0 = *(const f32x4*)ksrc1;
      Bk1 = *(const f32x4*)(ksrc1 + 4);
      Bk2 = *(const f32x4*)(ksrc1 + 8);
      Bk3 = *(const f32x4*)(ksrc1 + 12);
      const float* vsrc1 = Vb + (size_t)(64 + srow) * Dc + scol;
      Bv0 = *(const f32x4*)vsrc1;
      Bv1 = *(const f32x4*)(vsrc1 + 4);
      Bv2 = *(const f32x4*)(vsrc1 + 8);
      Bv3 = *(const f32x4*)(vsrc1 + 12);

      uint4v w0, w1;
      w0[0] = pk_bf16(a0[0], a0[1]); w0[1] = pk_bf16(a0[2], a0[3]);
      w0[2] = pk_bf16(a1[0], a1[1]); w0[3] = pk_bf16(a1[2], a1[3]);
      w1[0] = pk_bf16(a2[0], a2[1]); w1[1] = pk_bf16(a2[2], a2[3]);
      w1[2] = pk_bf16(a3[0], a3[1]); w1[3] = pk_bf16(a3[2], a3[3]);
      *(uint4v*)&k_lds[0][srow][scol ^ ssw]       = w0;
      *(uint4v*)&k_lds[0][srow][(scol + 8) ^ ssw] = w1;
      f32x4 bb[4] = { b0, b1, b2, b3 };
      #pragma unroll
      for (int c = 0; c < 4; ++c)
        #pragma unroll
        for (int e = 0; e < 4; ++e) {
          const int dd = scol + 4 * c + e;
          vt_lds[0][dd][srow ^ (vswz(dd) << 3)] = (__bf16)bb[c][e];
        }
    }
    __syncthreads();

    int bq = 0;                      // buffer of tile t; bp = t-1; bw = t+1
    for (int t = 0; t <= nkb; t += 2) {
      BODY(t, A, B);
      if (t + 1 <= nkb) { BODY(t + 1, B, A); }
    }

    // ---- epilogue: O^T regs -> rows of O ----
    const float inv = 1.0f / l;
    float* orow = Ob + (size_t)(wq + l31) * Dc;
    #pragma unroll
    for (int b = 0; b < 4; ++b) {
      f32x4 u0, u1;
      #pragma unroll
      for (int e = 0; e < 4; ++e) { u0[e] = o0[4 * b + e] * inv; u1[e] = o1[4 * b + e] * inv; }
      *(f32x4*)(orow + 8 * b + 4 * hi)      = u0;
      *(f32x4*)(orow + 32 + 8 * b + 4 * hi) = u1;
    }
    __syncthreads();  // LDS reuse guard before next panel's prologue
  }
#undef BODY
}

}  // namespace

extern "C" void kernel_launch(void* const* d_in, const int* in_sizes, int n_in,
                              void* d_out, int out_size, void* d_ws, size_t ws_size,
                              hipStream_t stream) {
  const float* q = (const float*)d_in[0];
  const float* k = (const float*)d_in[1];
  const float* v = (const float*)d_in[2];
  // d_in[3] (triu mask) applied analytically.
  float* o = (float*)d_out;
  dim3 grid(8, Bc * Hc);
  fattn_kernel<<<grid, dim3(256), 0, stream>>>(q, k, v, o);
}

// Round 15
// 75.219 us; speedup vs baseline: 1.1031x; 1.1031x over previous
//
#include <hip/hip_runtime.h>
#include <hip/hip_bf16.h>

namespace {

constexpr int Bc = 4, Hc = 16, Sc = 2048, Dc = 64;

using bf16x2 = __attribute__((ext_vector_type(2))) __bf16;
using bf16x8 = __attribute__((ext_vector_type(8))) __bf16;
using f32x4  = __attribute__((ext_vector_type(4))) float;
using f32x16 = __attribute__((ext_vector_type(16))) float;
using uint4v = __attribute__((ext_vector_type(4))) unsigned int;

__device__ __forceinline__ float exp2_hw(float x) {
#if __has_builtin(__builtin_amdgcn_exp2f)
  return __builtin_amdgcn_exp2f(x);
#else
  return exp2f(x);
#endif
}

__device__ __forceinline__ unsigned pk_bf16(float a, float b) {
  bf16x2 t = { (__bf16)a, (__bf16)b };
  return __builtin_bit_cast(unsigned, t);
}

// v_permlane32_swap_b32 a,b with s_nop hazard padding (raw asm bypasses the
// post-RA hazard recognizer). Operands must be DISTINCT live values.
__device__ __forceinline__ void pl32swap(unsigned& a, unsigned& b) {
  asm volatile("s_nop 1\n\tv_permlane32_swap_b32 %0, %1\n\ts_nop 1"
               : "+v"(a), "+v"(b));
}
// Early-clobber dual-mov guarantees the two swap operands sit in distinct regs
// (round-3 lesson: copies of one SSA value may share a VGPR).
__device__ __forceinline__ void xhalf_pair(float x, float& lo, float& hi) {
  unsigned a, b;
  asm volatile("v_mov_b32 %0, %2\n\t"
               "v_mov_b32 %1, %2\n\t"
               "s_nop 1\n\t"
               "v_permlane32_swap_b32 %0, %1\n\t"
               "s_nop 1"
               : "=&v"(a), "=&v"(b)
               : "v"(x));
  lo = __builtin_bit_cast(float, a);
  hi = __builtin_bit_cast(float, b);
}
__device__ __forceinline__ float xhalf_sum(float x) {
  float lo, hi; xhalf_pair(x, lo, hi); return lo + hi;
}

__device__ __forceinline__ int vswz(int d) { return ((d >> 4) ^ d) & 7; }

// ROUND-15 = round-13 (64 us best) with the staging pipeline rebuilt around
// RAW s_barrier (T3/T4). Round-14 lesson: __syncthreads() emits a full
// s_waitcnt vmcnt(0) before s_barrier, force-draining every staging load at
// the same-iteration barrier — no prefetch depth can help through it.
// New iteration order (single 32-VGPR staging set R, no r14 spill):
//   1. STAGE_WRITE tile t+1 from R (loaded a FULL PERIOD ago -> vmcnt ~free)
//   2. issue loads tile t+2 -> R (WAR on in-order issue is safe)
//   3. s_waitcnt lgkmcnt(0); raw s_barrier  (global loads stay in flight!)
//   4. compute: QK(t) || PV(t-1) || softmax(t)
// Write-at-top needs 4-buffer rotation: write buf[(t+1)&3] = buf(t-3), last
// read at iter t-2, barrier(t-1) between -> race-free. LDS 64KB/block,
// 2 blocks/CU = 128KB <= 160KB: residency unchanged.
__global__ __launch_bounds__(256, 2)
void fattn_kernel(const float* __restrict__ Q, const float* __restrict__ K,
                  const float* __restrict__ V, float* __restrict__ O) {
  const int tid  = threadIdx.x;
  const int wid  = tid >> 6;
  const int lane = tid & 63;
  const int l31  = lane & 31;
  const int hi   = lane >> 5;

  // XCD-bijective swizzle; pair-panels {p, 15-p} -> every block = 34 tiles.
  const int flat = blockIdx.x + 8 * blockIdx.y;
  const int w    = (flat & 7) * 64 + (flat >> 3);
  const int p    = w & 7;
  const int bh   = w >> 3;

  const size_t base = (size_t)bh * (Sc * Dc);
  const float* Qb = Q + base;
  const float* Kb = K + base;
  const float* Vb = V + base;
  float*       Ob = O + base;

  __shared__ __align__(16) __bf16 k_lds[4][64][64];   // K[k][d],  col ^= (k&7)<<3
  __shared__ __align__(16) __bf16 vt_lds[4][64][64];  // V^T[d][k], k ^= vswz(d)<<3

  const int srow = tid >> 2;         // staging row 0..63
  const int scol = (tid & 3) * 16;   // staging col chunk
  const int ssw  = (srow & 7) << 3;

  constexpr float QSC = 0.125f * 1.44269504088896f;  // 1/sqrt(D) * log2(e)

  for (int half = 0; half < 2; ++half) {
    const int qp = half ? (15 - p) : p;
    const int qb = qp * 128;
    const int wq = qb + wid * 32;
    const int nkb = 2 * qp + 2;
    const int tl  = 2 * qp + (wid >> 1);   // last causally-active tile for wave

    // ---- Q fragment: lane holds Q[wq + l31][d = s*16 + hi*8 + j] ----
    bf16x8 qf[4];
    {
      const float* qrow = Qb + (size_t)(wq + l31) * Dc;
      #pragma unroll
      for (int s = 0; s < 4; ++s) {
        const float* src = qrow + s * 16 + hi * 8;
        f32x4 a0 = *(const f32x4*)src;
        f32x4 a1 = *(const f32x4*)(src + 4);
        uint4v wv;
        wv[0] = pk_bf16(a0[0] * QSC, a0[1] * QSC);
        wv[1] = pk_bf16(a0[2] * QSC, a0[3] * QSC);
        wv[2] = pk_bf16(a1[0] * QSC, a1[1] * QSC);
        wv[3] = pk_bf16(a1[2] * QSC, a1[3] * QSC);
        qf[s] = __builtin_bit_cast(bf16x8, wv);
      }
    }

    f32x16 o0, o1;
    #pragma unroll
    for (int i = 0; i < 16; ++i) { o0[i] = 0.f; o1[i] = 0.f; }
    float l = 0.f;
    bf16x8 pfp0, pfp1, pfp2, pfp3;   // P fragments of tile t-1 (cross-iter)

    // single in-flight staging register set (tile t+1's data during iter t)
    f32x4 Rk0, Rk1, Rk2, Rk3, Rv0, Rv1, Rv2, Rv3;

    // ---- prologue: tile 0 -> buf 0 directly; tile 1 loads -> R ----
    {
      const float* ksrc = Kb + (size_t)srow * Dc + scol;
      f32x4 a0 = *(const f32x4*)ksrc;
      f32x4 a1 = *(const f32x4*)(ksrc + 4);
      f32x4 a2 = *(const f32x4*)(ksrc + 8);
      f32x4 a3 = *(const f32x4*)(ksrc + 12);
      const float* vsrc = Vb + (size_t)srow * Dc + scol;
      f32x4 b0 = *(const f32x4*)vsrc;
      f32x4 b1 = *(const f32x4*)(vsrc + 4);
      f32x4 b2 = *(const f32x4*)(vsrc + 8);
      f32x4 b3 = *(const f32x4*)(vsrc + 12);
      uint4v w0, w1;
      w0[0] = pk_bf16(a0[0], a0[1]); w0[1] = pk_bf16(a0[2], a0[3]);
      w0[2] = pk_bf16(a1[0], a1[1]); w0[3] = pk_bf16(a1[2], a1[3]);
      w1[0] = pk_bf16(a2[0], a2[1]); w1[1] = pk_bf16(a2[2], a2[3]);
      w1[2] = pk_bf16(a3[0], a3[1]); w1[3] = pk_bf16(a3[2], a3[3]);
      *(uint4v*)&k_lds[0][srow][scol ^ ssw]       = w0;
      *(uint4v*)&k_lds[0][srow][(scol + 8) ^ ssw] = w1;
      f32x4 bb[4] = { b0, b1, b2, b3 };
      #pragma unroll
      for (int c = 0; c < 4; ++c)
        #pragma unroll
        for (int e = 0; e < 4; ++e) {
          const int dd = scol + 4 * c + e;
          vt_lds[0][dd][srow ^ (vswz(dd) << 3)] = (__bf16)bb[c][e];
        }
      // tile 1 (nkb >= 2 always)
      const float* ksrc1 = Kb + (size_t)(64 + srow) * Dc + scol;
      Rk0 = *(const f32x4*)ksrc1;
      Rk1 = *(const f32x4*)(ksrc1 + 4);
      Rk2 = *(const f32x4*)(ksrc1 + 8);
      Rk3 = *(const f32x4*)(ksrc1 + 12);
      const float* vsrc1 = Vb + (size_t)(64 + srow) * Dc + scol;
      Rv0 = *(const f32x4*)vsrc1;
      Rv1 = *(const f32x4*)(vsrc1 + 4);
      Rv2 = *(const f32x4*)(vsrc1 + 8);
      Rv3 = *(const f32x4*)(vsrc1 + 12);
    }

    for (int t = 0; t <= nkb; ++t) {
      const int bq = t & 3;
      const int bp = (t - 1) & 3;
      const int bw = (t + 1) & 3;
      const int kbase = t * 64;
      const bool doQK = (t < nkb) && (t <= tl);
      const bool doPV = (t >= 1) && (t - 1 <= tl);

      // ---- 1. STAGE_WRITE tile t+1 from R (loads are a full period old) ----
      if (t + 1 < nkb) {
        uint4v w0, w1;
        w0[0] = pk_bf16(Rk0[0], Rk0[1]); w0[1] = pk_bf16(Rk0[2], Rk0[3]);
        w0[2] = pk_bf16(Rk1[0], Rk1[1]); w0[3] = pk_bf16(Rk1[2], Rk1[3]);
        w1[0] = pk_bf16(Rk2[0], Rk2[1]); w1[1] = pk_bf16(Rk2[2], Rk2[3]);
        w1[2] = pk_bf16(Rk3[0], Rk3[1]); w1[3] = pk_bf16(Rk3[2], Rk3[3]);
        *(uint4v*)&k_lds[bw][srow][scol ^ ssw]       = w0;
        *(uint4v*)&k_lds[bw][srow][(scol + 8) ^ ssw] = w1;
        #pragma unroll
        for (int e = 0; e < 4; ++e) {
          vt_lds[bw][scol + e     ][srow ^ (vswz(scol + e     ) << 3)] = (__bf16)Rv0[e];
          vt_lds[bw][scol + 4 + e ][srow ^ (vswz(scol + 4 + e ) << 3)] = (__bf16)Rv1[e];
          vt_lds[bw][scol + 8 + e ][srow ^ (vswz(scol + 8 + e ) << 3)] = (__bf16)Rv2[e];
          vt_lds[bw][scol + 12 + e][srow ^ (vswz(scol + 12 + e) << 3)] = (__bf16)Rv3[e];
        }
      }

      // ---- 2. issue loads tile t+2 -> R (in flight across the barrier) ----
      if (t + 2 < nkb) {
        const float* ksrc = Kb + (size_t)(kbase + 128 + srow) * Dc + scol;
        Rk0 = *(const f32x4*)ksrc;
        Rk1 = *(const f32x4*)(ksrc + 4);
        Rk2 = *(const f32x4*)(ksrc + 8);
        Rk3 = *(const f32x4*)(ksrc + 12);
        const float* vsrc = Vb + (size_t)(kbase + 128 + srow) * Dc + scol;
        Rv0 = *(const f32x4*)vsrc;
        Rv1 = *(const f32x4*)(vsrc + 4);
        Rv2 = *(const f32x4*)(vsrc + 8);
        Rv3 = *(const f32x4*)(vsrc + 12);
      }

      // ---- 3. LDS visibility fence + RAW barrier (vmcnt NOT drained) ----
      asm volatile("s_waitcnt lgkmcnt(0)" ::: "memory");
      __builtin_amdgcn_s_barrier();

      // ---- 4a. QK(t): S^T = K * Q^T from k_lds[bq] ----
      f32x16 s0, s1;
      if (doQK) {
        #pragma unroll
        for (int i = 0; i < 16; ++i) { s0[i] = 0.f; s1[i] = 0.f; }
        const int ksw = (l31 & 7) << 3;
        __builtin_amdgcn_s_setprio(1);
        #pragma unroll
        for (int s = 0; s < 4; ++s) {
          bf16x8 kf = *(const bf16x8*)&k_lds[bq][l31][(s * 16 + hi * 8) ^ ksw];
          s0 = __builtin_amdgcn_mfma_f32_32x32x16_bf16(kf, qf[s], s0, 0, 0, 0);
        }
        #pragma unroll
        for (int s = 0; s < 4; ++s) {
          bf16x8 kf = *(const bf16x8*)&k_lds[bq][32 + l31][(s * 16 + hi * 8) ^ ksw];
          s1 = __builtin_amdgcn_mfma_f32_32x32x16_bf16(kf, qf[s], s1, 0, 0, 0);
        }
        __builtin_amdgcn_s_setprio(0);
      }

      // ---- 4b. PV(t-1) from vt_lds[bp] (independent of QK(t)) ----
      if (doPV) {
        const int vd0 = l31, vd1 = 32 + l31;
        const int vs0 = vswz(vd0) << 3, vs1 = vswz(vd1) << 3;
        const __bf16 (*vc)[64] = vt_lds[bp];
        bf16x8 vf;
        __builtin_amdgcn_s_setprio(1);
        vf = *(const bf16x8*)&vc[vd0][(hi * 8) ^ vs0];
        o0 = __builtin_amdgcn_mfma_f32_32x32x16_bf16(vf, pfp0, o0, 0, 0, 0);
        vf = *(const bf16x8*)&vc[vd0][(16 + hi * 8) ^ vs0];
        o0 = __builtin_amdgcn_mfma_f32_32x32x16_bf16(vf, pfp1, o0, 0, 0, 0);
        vf = *(const bf16x8*)&vc[vd0][(32 + hi * 8) ^ vs0];
        o0 = __builtin_amdgcn_mfma_f32_32x32x16_bf16(vf, pfp2, o0, 0, 0, 0);
        vf = *(const bf16x8*)&vc[vd0][(48 + hi * 8) ^ vs0];
        o0 = __builtin_amdgcn_mfma_f32_32x32x16_bf16(vf, pfp3, o0, 0, 0, 0);
        vf = *(const bf16x8*)&vc[vd1][(hi * 8) ^ vs1];
        o1 = __builtin_amdgcn_mfma_f32_32x32x16_bf16(vf, pfp0, o1, 0, 0, 0);
        vf = *(const bf16x8*)&vc[vd1][(16 + hi * 8) ^ vs1];
        o1 = __builtin_amdgcn_mfma_f32_32x32x16_bf16(vf, pfp1, o1, 0, 0, 0);
        vf = *(const bf16x8*)&vc[vd1][(32 + hi * 8) ^ vs1];
        o1 = __builtin_amdgcn_mfma_f32_32x32x16_bf16(vf, pfp2, o1, 0, 0, 0);
        vf = *(const bf16x8*)&vc[vd1][(48 + hi * 8) ^ vs1];
        o1 = __builtin_amdgcn_mfma_f32_32x32x16_bf16(vf, pfp3, o1, 0, 0, 0);
        __builtin_amdgcn_s_setprio(0);
      }

      // ---- 4c. softmax(t): mask, exp2, sum, cvt_pk -> pfp ----
      if (doQK) {
        if (kbase + 63 > wq) {
          const int q   = wq + l31;
          const int dq0 = q - (kbase + 4 * hi);
          const int dq1 = q - (kbase + 32 + 4 * hi);
          #pragma unroll
          for (int i = 0; i < 16; ++i) {
            const int off = (i & 3) + 8 * (i >> 2);
            if (off > dq0) s0[i] = -1e30f;
            if (off > dq1) s1[i] = -1e30f;
          }
        }
        #pragma unroll
        for (int i = 0; i < 16; ++i) {
          s0[i] = exp2_hw(s0[i]);
          s1[i] = exp2_hw(s1[i]);
        }
        float sm[16];
        #pragma unroll
        for (int i = 0; i < 16; ++i) sm[i] = s0[i] + s1[i];
        #pragma unroll
        for (int st = 8; st > 0; st >>= 1)
          #pragma unroll
          for (int i = 0; i < st; ++i) sm[i] += sm[i + st];
        l += xhalf_sum(sm[0]);

        uint4v wv;
        unsigned t0, t1, t2, t3;
        t0 = pk_bf16(s0[0], s0[1]);  t1 = pk_bf16(s0[2], s0[3]);
        t2 = pk_bf16(s0[4], s0[5]);  t3 = pk_bf16(s0[6], s0[7]);
        pl32swap(t0, t2); pl32swap(t1, t3);
        wv[0] = t0; wv[1] = t1; wv[2] = t2; wv[3] = t3;
        pfp0 = __builtin_bit_cast(bf16x8, wv);
        t0 = pk_bf16(s0[8], s0[9]);   t1 = pk_bf16(s0[10], s0[11]);
        t2 = pk_bf16(s0[12], s0[13]); t3 = pk_bf16(s0[14], s0[15]);
        pl32swap(t0, t2); pl32swap(t1, t3);
        wv[0] = t0; wv[1] = t1; wv[2] = t2; wv[3] = t3;
        pfp1 = __builtin_bit_cast(bf16x8, wv);
        t0 = pk_bf16(s1[0], s1[1]);  t1 = pk_bf16(s1[2], s1[3]);
        t2 = pk_bf16(s1[4], s1[5]);  t3 = pk_bf16(s1[6], s1[7]);
        pl32swap(t0, t2); pl32swap(t1, t3);
        wv[0] = t0; wv[1] = t1; wv[2] = t2; wv[3] = t3;
        pfp2 = __builtin_bit_cast(bf16x8, wv);
        t0 = pk_bf16(s1[8], s1[9]);   t1 = pk_bf16(s1[10], s1[11]);
        t2 = pk_bf16(s1[12], s1[13]); t3 = pk_bf16(s1[14], s1[15]);
        pl32swap(t0, t2); pl32swap(t1, t3);
        wv[0] = t0; wv[1] = t1; wv[2] = t2; wv[3] = t3;
        pfp3 = __builtin_bit_cast(bf16x8, wv);
      }
    }

    // ---- epilogue: O^T regs -> rows of O ----
    const float inv = 1.0f / l;
    float* orow = Ob + (size_t)(wq + l31) * Dc;
    #pragma unroll
    for (int b = 0; b < 4; ++b) {
      f32x4 u0, u1;
      #pragma unroll
      for (int e = 0; e < 4; ++e) { u0[e] = o0[4 * b + e] * inv; u1[e] = o1[4 * b + e] * inv; }
      *(f32x4*)(orow + 8 * b + 4 * hi)      = u0;
      *(f32x4*)(orow + 32 + 8 * b + 4 * hi) = u1;
    }
    __syncthreads();  // full drain once per panel: LDS reuse guard
  }
}

}  // namespace

extern "C" void kernel_launch(void* const* d_in, const int* in_sizes, int n_in,
                              void* d_out, int out_size, void* d_ws, size_t ws_size,
                              hipStream_t stream) {
  const float* q = (const float*)d_in[0];
  const float* k = (const float*)d_in[1];
  const float* v = (const float*)d_in[2];
  // d_in[3] (triu mask) applied analytically.
  float* o = (float*)d_out;
  dim3 grid(8, Bc * Hc);
  fattn_kernel<<<grid, dim3(256), 0, stream>>>(q, k, v, o);
}